// Round 1
// baseline (504.860 us; speedup 1.0000x reference)
//
#include <hip/hip_runtime.h>
#include <math.h>

// Problem constants
#define BB     32
#define NBANDS 9
#define NCHAN  64
#define NTIME  4096
#define CC     288           // 32*9
#define TLEN   7
#define NSEG   8
#define SEGLEN 512           // NTIME/8
#define NCLASS 4

// ws layout (floats)
#define WS_WF    0                      // 288*64
#define WS_BIAS  (WS_WF + CC*NCHAN)     // 288
#define WS_S1    (WS_BIAS + CC)         // 32*288*8
#define WS_S2    (WS_S1 + BB*CC*NSEG)   // 32*288*8
#define WS_FLAT  (WS_S2 + BB*CC*NSEG)   // 32*4032
#define WS_TOTAL (WS_FLAT + BB*CC*TLEN*2)

// ---------------- K0: fold renorm(conv_w,2) + BN(eval) into W,bias ----------
__global__ __launch_bounds__(64) void k0_fold(
    const float* __restrict__ cw, const float* __restrict__ cb,
    const float* __restrict__ gam, const float* __restrict__ bet,
    const float* __restrict__ mu, const float* __restrict__ var,
    float* __restrict__ Wf, float* __restrict__ biasf) {
  int c = blockIdx.x;
  int h = threadIdx.x;
  float w = cw[c * NCHAN + h];
  float sq = w * w;
#pragma unroll
  for (int off = 32; off; off >>= 1) sq += __shfl_down(sq, off, 64);
  sq = __shfl(sq, 0, 64);
  float norm = sqrtf(sq);
  float scale = fminf(1.0f, 2.0f / fmaxf(norm, 1e-7f));
  float bns = gam[c] / sqrtf(var[c] + 1e-5f);
  Wf[c * NCHAN + h] = w * scale * bns;
  if (h == 0) biasf[c] = (cb[c] - mu[c]) * bns + bet[c];
}

// ---------------- K1: fused conv + BN + swish + per-segment moment sums -----
// grid: 32 b * 9 g * 8 seg = 2304 blocks, 256 threads. Each thread owns two
// time points (t, t+256) of one 512-wide segment; x columns (64 h) live in
// VGPRs, W[c][h] is wave-uniform -> s_load. Block-reduces sum(y), sum(y^2)
// per output channel.
__global__ __launch_bounds__(256) void k1_conv(
    const float* __restrict__ x, const float* __restrict__ Wf,
    const float* __restrict__ biasf,
    float* __restrict__ S1, float* __restrict__ S2) {
  int gid = blockIdx.x;
  int seg = gid & 7;
  int g = (gid >> 3) % NBANDS;
  int b = gid / (NBANDS * NSEG);
  int tid = threadIdx.x;
  int tA = seg * SEGLEN + tid;
  int tB = tA + 256;
  const float* xp = x + (size_t)(b * NBANDS + g) * NCHAN * NTIME;

  float xa[NCHAN], xb[NCHAN];
#pragma unroll
  for (int h = 0; h < NCHAN; ++h) {
    xa[h] = xp[h * NTIME + tA];
    xb[h] = xp[h * NTIME + tB];
  }

  __shared__ float part[32][4][2];
  int wave = tid >> 6;
  int lane = tid & 63;
  const float* wbase = Wf + g * 32 * NCHAN;
  const float* bbase = biasf + g * 32;

  for (int c = 0; c < 32; ++c) {
    const float* wc = wbase + c * NCHAN;   // wave-uniform -> SGPR loads
    float bias = bbase[c];
    float da = bias, db = bias;
#pragma unroll
    for (int h = 0; h < NCHAN; ++h) {
      float w = wc[h];
      da = fmaf(w, xa[h], da);
      db = fmaf(w, xb[h], db);
    }
    // swish
    float ya = da / (1.0f + __expf(-da));
    float yb = db / (1.0f + __expf(-db));
    float s1 = ya + yb;
    float s2 = ya * ya + yb * yb;
#pragma unroll
    for (int off = 32; off; off >>= 1) {
      s1 += __shfl_down(s1, off, 64);
      s2 += __shfl_down(s2, off, 64);
    }
    if (lane == 0) { part[c][wave][0] = s1; part[c][wave][1] = s2; }
  }
  __syncthreads();
  if (tid < 64) {
    int c = tid >> 1;
    int which = tid & 1;
    float v = part[c][0][which] + part[c][1][which] +
              part[c][2][which] + part[c][3][which];
    size_t o = (size_t)((b * CC) + g * 32 + c) * NSEG + seg;
    if (which == 0) S1[o] = v; else S2[o] = v;
  }
}

// ---------------- K2: tempo features + per-(b,c) 7x2 MHSA + out_proj --------
__global__ __launch_bounds__(256) void k2_attn(
    const float* __restrict__ S1, const float* __restrict__ S2,
    const float* __restrict__ ipw, const float* __restrict__ ipb,
    const float* __restrict__ opw, const float* __restrict__ opb,
    float* __restrict__ flat) {
  int idx = blockIdx.x * blockDim.x + threadIdx.x;
  if (idx >= BB * CC) return;
  int b = idx / CC, c = idx % CC;
  const float* s1 = S1 + (size_t)(b * CC + c) * NSEG;
  const float* s2 = S2 + (size_t)(b * CC + c) * NSEG;

  float yq[TLEN][2];
#pragma unroll
  for (int t = 0; t < TLEN; ++t) {
    float S1w = s1[t] + s1[t + 1];
    float S2w = s2[t] + s2[t + 1];
    float mean = S1w * (1.0f / 1024.0f);
    float var = (S2w - S1w * S1w * (1.0f / 1024.0f)) * (1.0f / 1023.0f);
    var = fminf(fmaxf(var, 1e-6f), 1e6f);
    float rms = sqrtf(S2w * (1.0f / 1024.0f));
    yq[t][0] = logf(var) + sinf((float)t);       // feat0 + pos_embed sin
    yq[t][1] = rms / mean + cosf((float)t);      // feat1 + pos_embed cos
  }

  const float* W = ipw + c * 12;   // [f][e], f in 0..5
  const float* Bp = ipb + c * 6;
  float q[TLEN][2], k[TLEN][2], v[TLEN][2];
#pragma unroll
  for (int t = 0; t < TLEN; ++t) {
#pragma unroll
    for (int f = 0; f < 6; ++f) {
      float val = W[f * 2 + 0] * yq[t][0] + W[f * 2 + 1] * yq[t][1] + Bp[f];
      if (f < 2) q[t][f] = val;
      else if (f < 4) k[t][f - 2] = val;
      else v[t][f - 4] = val;
    }
  }

  float o[TLEN][2];
#pragma unroll
  for (int h = 0; h < 2; ++h) {
#pragma unroll
    for (int t = 0; t < TLEN; ++t) {
      float sc[TLEN];
      float m = -1e30f;
#pragma unroll
      for (int s = 0; s < TLEN; ++s) {
        sc[s] = q[t][h] * k[s][h];     // head_dim=1, scale=1
        m = fmaxf(m, sc[s]);
      }
      float sum = 0.0f, acc = 0.0f;
#pragma unroll
      for (int s = 0; s < TLEN; ++s) {
        float e = expf(sc[s] - m);
        sum += e;
        acc += e * v[s][h];
      }
      o[t][h] = acc / sum;
    }
  }

  const float* Wo = opw + c * 4;
  const float* Bo = opb + c * 2;
  float* out = flat + (size_t)b * (CC * TLEN * 2) + c * (TLEN * 2);
#pragma unroll
  for (int t = 0; t < TLEN; ++t) {
    out[t * 2 + 0] = Wo[0] * o[t][0] + Wo[1] * o[t][1] + Bo[0];
    out[t * 2 + 1] = Wo[2] * o[t][0] + Wo[3] * o[t][1] + Bo[1];
  }
}

// ---------------- K3: classifier with renorm(last_w,0.5) + log_softmax ------
__global__ __launch_bounds__(256) void k3_cls(
    const float* __restrict__ flat, const float* __restrict__ lw,
    const float* __restrict__ lb, float* __restrict__ out) {
  const int FEAT = CC * TLEN * 2;  // 4032
  int b = blockIdx.x;
  int tid = threadIdx.x;
  const float* f = flat + (size_t)b * FEAT;
  float d[NCLASS] = {0, 0, 0, 0}, n2[NCLASS] = {0, 0, 0, 0};
  for (int j = tid; j < FEAT; j += 256) {
    float fv = f[j];
#pragma unroll
    for (int n = 0; n < NCLASS; ++n) {
      float w = lw[n * FEAT + j];
      d[n] = fmaf(fv, w, d[n]);
      n2[n] = fmaf(w, w, n2[n]);
    }
  }
  __shared__ float red[4][8];
  int lane = tid & 63, wave = tid >> 6;
#pragma unroll
  for (int n = 0; n < NCLASS; ++n) {
#pragma unroll
    for (int off = 32; off; off >>= 1) {
      d[n] += __shfl_down(d[n], off, 64);
      n2[n] += __shfl_down(n2[n], off, 64);
    }
  }
  if (lane == 0) {
#pragma unroll
    for (int n = 0; n < NCLASS; ++n) {
      red[wave][n] = d[n];
      red[wave][n + 4] = n2[n];
    }
  }
  __syncthreads();
  if (tid == 0) {
    float logit[NCLASS];
#pragma unroll
    for (int n = 0; n < NCLASS; ++n) {
      float dn = red[0][n] + red[1][n] + red[2][n] + red[3][n];
      float nn = red[0][n + 4] + red[1][n + 4] + red[2][n + 4] + red[3][n + 4];
      float norm = sqrtf(nn);
      float scale = fminf(1.0f, 0.5f / fmaxf(norm, 1e-7f));
      logit[n] = dn * scale + lb[n];
    }
    float m = fmaxf(fmaxf(logit[0], logit[1]), fmaxf(logit[2], logit[3]));
    float s = 0.0f;
#pragma unroll
    for (int n = 0; n < NCLASS; ++n) s += expf(logit[n] - m);
    float ls = logf(s);
#pragma unroll
    for (int n = 0; n < NCLASS; ++n) out[b * NCLASS + n] = logit[n] - m - ls;
  }
}

extern "C" void kernel_launch(void* const* d_in, const int* in_sizes, int n_in,
                              void* d_out, int out_size, void* d_ws, size_t ws_size,
                              hipStream_t stream) {
  const float* x     = (const float*)d_in[0];
  const float* cw    = (const float*)d_in[1];
  const float* cb    = (const float*)d_in[2];
  const float* gam   = (const float*)d_in[3];
  const float* bet   = (const float*)d_in[4];
  const float* mu    = (const float*)d_in[5];
  const float* var   = (const float*)d_in[6];
  const float* ipw   = (const float*)d_in[7];
  const float* ipb   = (const float*)d_in[8];
  const float* opw   = (const float*)d_in[9];
  const float* opb   = (const float*)d_in[10];
  const float* lw    = (const float*)d_in[11];
  const float* lb    = (const float*)d_in[12];
  float* out = (float*)d_out;

  float* ws = (float*)d_ws;
  float* Wf    = ws + WS_WF;
  float* biasf = ws + WS_BIAS;
  float* S1    = ws + WS_S1;
  float* S2    = ws + WS_S2;
  float* flat  = ws + WS_FLAT;

  k0_fold<<<CC, 64, 0, stream>>>(cw, cb, gam, bet, mu, var, Wf, biasf);
  k1_conv<<<BB * NBANDS * NSEG, 256, 0, stream>>>(x, Wf, biasf, S1, S2);
  k2_attn<<<(BB * CC + 255) / 256, 256, 0, stream>>>(S1, S2, ipw, ipb, opw, opb, flat);
  k3_cls<<<BB, 256, 0, stream>>>(flat, lw, lb, out);
}

// Round 2
// 455.593 us; speedup vs baseline: 1.1081x; 1.1081x over previous
//
#include <hip/hip_runtime.h>
#include <math.h>

// Problem constants
#define BB     32
#define NBANDS 9
#define NCHAN  64
#define NTIME  4096
#define CC     288           // 32*9
#define TLEN   7
#define NSEG   8
#define SEGLEN 512           // NTIME/8
#define NCLASS 4

// ws layout (floats)
#define WS_WF    0                      // 288*64
#define WS_BIAS  (WS_WF + CC*NCHAN)     // 288
#define WS_S1    (WS_BIAS + CC)         // 32*288*8
#define WS_S2    (WS_S1 + BB*CC*NSEG)   // 32*288*8
#define WS_FLAT  (WS_S2 + BB*CC*NSEG)   // 32*4032
#define WS_TOTAL (WS_FLAT + BB*CC*TLEN*2)

// ---------------- K0: fold renorm(conv_w,2) + BN(eval) into W,bias ----------
__global__ __launch_bounds__(64) void k0_fold(
    const float* __restrict__ cw, const float* __restrict__ cb,
    const float* __restrict__ gam, const float* __restrict__ bet,
    const float* __restrict__ mu, const float* __restrict__ var,
    float* __restrict__ Wf, float* __restrict__ biasf) {
  int c = blockIdx.x;
  int h = threadIdx.x;
  float w = cw[c * NCHAN + h];
  float sq = w * w;
#pragma unroll
  for (int off = 32; off; off >>= 1) sq += __shfl_down(sq, off, 64);
  sq = __shfl(sq, 0, 64);
  float norm = sqrtf(sq);
  float scale = fminf(1.0f, 2.0f / fmaxf(norm, 1e-7f));
  float bns = gam[c] / sqrtf(var[c] + 1e-5f);
  Wf[c * NCHAN + h] = w * scale * bns;
  if (h == 0) biasf[c] = (cb[c] - mu[c]) * bns + bet[c];
}

// ---------------- K1: fused conv + BN + swish + per-segment moment sums -----
// grid: 32 b * 9 g * 8 seg = 2304 blocks, 256 threads. Each thread owns two
// CONSECUTIVE time points (float2 load) of one 512-wide segment.
// Register plan: acc[32]x2 = 64 VGPRs resident; x streamed in h-tiles of 8
// (8 float2 = 16 VGPRs live) -> ~95 VGPR total, no demotion/spill.
// W[c][h] is wave-uniform -> scalar loads (s_load_dwordx8), zero VMEM cost.
__global__ __launch_bounds__(256, 4) void k1_conv(
    const float* __restrict__ x, const float* __restrict__ Wf,
    const float* __restrict__ biasf,
    float* __restrict__ S1, float* __restrict__ S2) {
  int gid = blockIdx.x;
  int seg = gid & 7;
  int g = (gid >> 3) % NBANDS;
  int b = gid / (NBANDS * NSEG);
  int tid = threadIdx.x;
  // base of this (b,g) image, at this segment's first time point
  const float* xp = x + (size_t)(b * NBANDS + g) * NCHAN * NTIME + seg * SEGLEN;
  const float* wbase = Wf + g * 32 * NCHAN;
  const float* bbase = biasf + g * 32;

  float acc0[32], acc1[32];
#pragma unroll
  for (int c = 0; c < 32; ++c) { acc0[c] = 0.0f; acc1[c] = 0.0f; }

#pragma unroll 1   // keep ht loop rolled: icache stays small, xv stays hot
  for (int ht = 0; ht < NCHAN; ht += 8) {
    float2 xv[8];
#pragma unroll
    for (int j = 0; j < 8; ++j)
      xv[j] = ((const float2*)(xp + (size_t)(ht + j) * NTIME))[tid];
#pragma unroll     // FULL unroll: constant indices keep acc[] in registers
    for (int c = 0; c < 32; ++c) {
#pragma unroll
      for (int j = 0; j < 8; ++j) {
        float w = wbase[c * NCHAN + ht + j];   // wave-uniform -> SGPR
        acc0[c] = fmaf(w, xv[j].x, acc0[c]);
        acc1[c] = fmaf(w, xv[j].y, acc1[c]);
      }
    }
  }

  __shared__ float part[32][4][2];
  int wave = tid >> 6;
  int lane = tid & 63;

#pragma unroll
  for (int c = 0; c < 32; ++c) {
    float bias = bbase[c];
    float da = acc0[c] + bias;
    float db = acc1[c] + bias;
    // swish via fast exp + hw rcp (threshold is 0.14; we're at 4e-3)
    float ya = da * __builtin_amdgcn_rcpf(1.0f + __expf(-da));
    float yb = db * __builtin_amdgcn_rcpf(1.0f + __expf(-db));
    float s1 = ya + yb;
    float s2 = fmaf(ya, ya, yb * yb);
#pragma unroll
    for (int off = 32; off; off >>= 1) {
      s1 += __shfl_down(s1, off, 64);
      s2 += __shfl_down(s2, off, 64);
    }
    if (lane == 0) { part[c][wave][0] = s1; part[c][wave][1] = s2; }
  }
  __syncthreads();
  if (tid < 64) {
    int c = tid >> 1;
    int which = tid & 1;
    float v = part[c][0][which] + part[c][1][which] +
              part[c][2][which] + part[c][3][which];
    size_t o = (size_t)((b * CC) + g * 32 + c) * NSEG + seg;
    if (which == 0) S1[o] = v; else S2[o] = v;
  }
}

// ---------------- K2: tempo features + per-(b,c) 7x2 MHSA + out_proj --------
__global__ __launch_bounds__(256) void k2_attn(
    const float* __restrict__ S1, const float* __restrict__ S2,
    const float* __restrict__ ipw, const float* __restrict__ ipb,
    const float* __restrict__ opw, const float* __restrict__ opb,
    float* __restrict__ flat) {
  // pos-embed for T=7, omega=1: sin(t), cos(t) — compile-time constants
  const float PSIN[TLEN] = {0.0f, 0.8414709848f, 0.9092974268f, 0.1411200081f,
                            -0.7568024953f, -0.9589242747f, -0.2794154982f};
  const float PCOS[TLEN] = {1.0f, 0.5403023059f, -0.4161468365f, -0.9899924966f,
                            -0.6536436209f, 0.2836621855f, 0.9601702867f};
  int idx = blockIdx.x * blockDim.x + threadIdx.x;
  if (idx >= BB * CC) return;
  int b = idx / CC, c = idx % CC;
  const float* s1 = S1 + (size_t)(b * CC + c) * NSEG;
  const float* s2 = S2 + (size_t)(b * CC + c) * NSEG;

  float yq[TLEN][2];
#pragma unroll
  for (int t = 0; t < TLEN; ++t) {
    float S1w = s1[t] + s1[t + 1];
    float S2w = s2[t] + s2[t + 1];
    float mean = S1w * (1.0f / 1024.0f);
    float var = (S2w - S1w * S1w * (1.0f / 1024.0f)) * (1.0f / 1023.0f);
    var = fminf(fmaxf(var, 1e-6f), 1e6f);
    float rms = sqrtf(S2w * (1.0f / 1024.0f));
    yq[t][0] = __logf(var) + PSIN[t];
    yq[t][1] = rms / mean + PCOS[t];
  }

  const float* W = ipw + c * 12;   // [f][e], f in 0..5
  const float* Bp = ipb + c * 6;
  float q[TLEN][2], k[TLEN][2], v[TLEN][2];
#pragma unroll
  for (int t = 0; t < TLEN; ++t) {
#pragma unroll
    for (int f = 0; f < 6; ++f) {
      float val = W[f * 2 + 0] * yq[t][0] + W[f * 2 + 1] * yq[t][1] + Bp[f];
      if (f < 2) q[t][f] = val;
      else if (f < 4) k[t][f - 2] = val;
      else v[t][f - 4] = val;
    }
  }

  float o[TLEN][2];
#pragma unroll
  for (int h = 0; h < 2; ++h) {
#pragma unroll
    for (int t = 0; t < TLEN; ++t) {
      float sc[TLEN];
      float m = -1e30f;
#pragma unroll
      for (int s = 0; s < TLEN; ++s) {
        sc[s] = q[t][h] * k[s][h];     // head_dim=1, scale=1
        m = fmaxf(m, sc[s]);
      }
      float sum = 0.0f, acc = 0.0f;
#pragma unroll
      for (int s = 0; s < TLEN; ++s) {
        float e = __expf(sc[s] - m);
        sum += e;
        acc += e * v[s][h];
      }
      o[t][h] = acc / sum;
    }
  }

  const float* Wo = opw + c * 4;
  const float* Bo = opb + c * 2;
  float* out = flat + (size_t)b * (CC * TLEN * 2) + c * (TLEN * 2);
#pragma unroll
  for (int t = 0; t < TLEN; ++t) {
    out[t * 2 + 0] = Wo[0] * o[t][0] + Wo[1] * o[t][1] + Bo[0];
    out[t * 2 + 1] = Wo[2] * o[t][0] + Wo[3] * o[t][1] + Bo[1];
  }
}

// ---------------- K3: classifier with renorm(last_w,0.5) + log_softmax ------
__global__ __launch_bounds__(256) void k3_cls(
    const float* __restrict__ flat, const float* __restrict__ lw,
    const float* __restrict__ lb, float* __restrict__ out) {
  const int FEAT = CC * TLEN * 2;  // 4032
  int b = blockIdx.x;
  int tid = threadIdx.x;
  const float* f = flat + (size_t)b * FEAT;
  float d[NCLASS] = {0, 0, 0, 0}, n2[NCLASS] = {0, 0, 0, 0};
  for (int j = tid; j < FEAT; j += 256) {
    float fv = f[j];
#pragma unroll
    for (int n = 0; n < NCLASS; ++n) {
      float w = lw[n * FEAT + j];
      d[n] = fmaf(fv, w, d[n]);
      n2[n] = fmaf(w, w, n2[n]);
    }
  }
  __shared__ float red[4][8];
  int lane = tid & 63, wave = tid >> 6;
#pragma unroll
  for (int n = 0; n < NCLASS; ++n) {
#pragma unroll
    for (int off = 32; off; off >>= 1) {
      d[n] += __shfl_down(d[n], off, 64);
      n2[n] += __shfl_down(n2[n], off, 64);
    }
  }
  if (lane == 0) {
#pragma unroll
    for (int n = 0; n < NCLASS; ++n) {
      red[wave][n] = d[n];
      red[wave][n + 4] = n2[n];
    }
  }
  __syncthreads();
  if (tid == 0) {
    float logit[NCLASS];
#pragma unroll
    for (int n = 0; n < NCLASS; ++n) {
      float dn = red[0][n] + red[1][n] + red[2][n] + red[3][n];
      float nn = red[0][n + 4] + red[1][n + 4] + red[2][n + 4] + red[3][n + 4];
      float norm = sqrtf(nn);
      float scale = fminf(1.0f, 0.5f / fmaxf(norm, 1e-7f));
      logit[n] = dn * scale + lb[n];
    }
    float m = fmaxf(fmaxf(logit[0], logit[1]), fmaxf(logit[2], logit[3]));
    float s = 0.0f;
#pragma unroll
    for (int n = 0; n < NCLASS; ++n) s += expf(logit[n] - m);
    float ls = logf(s);
#pragma unroll
    for (int n = 0; n < NCLASS; ++n) out[b * NCLASS + n] = logit[n] - m - ls;
  }
}

extern "C" void kernel_launch(void* const* d_in, const int* in_sizes, int n_in,
                              void* d_out, int out_size, void* d_ws, size_t ws_size,
                              hipStream_t stream) {
  const float* x     = (const float*)d_in[0];
  const float* cw    = (const float*)d_in[1];
  const float* cb    = (const float*)d_in[2];
  const float* gam   = (const float*)d_in[3];
  const float* bet   = (const float*)d_in[4];
  const float* mu    = (const float*)d_in[5];
  const float* var   = (const float*)d_in[6];
  const float* ipw   = (const float*)d_in[7];
  const float* ipb   = (const float*)d_in[8];
  const float* opw   = (const float*)d_in[9];
  const float* opb   = (const float*)d_in[10];
  const float* lw    = (const float*)d_in[11];
  const float* lb    = (const float*)d_in[12];
  float* out = (float*)d_out;

  float* ws = (float*)d_ws;
  float* Wf    = ws + WS_WF;
  float* biasf = ws + WS_BIAS;
  float* S1    = ws + WS_S1;
  float* S2    = ws + WS_S2;
  float* flat  = ws + WS_FLAT;

  k0_fold<<<CC, 64, 0, stream>>>(cw, cb, gam, bet, mu, var, Wf, biasf);
  k1_conv<<<BB * NBANDS * NSEG, 256, 0, stream>>>(x, Wf, biasf, S1, S2);
  k2_attn<<<(BB * CC + 255) / 256, 256, 0, stream>>>(S1, S2, ipw, ipb, opw, opb, flat);
  k3_cls<<<BB, 256, 0, stream>>>(flat, lw, lb, out);
}

// Round 4
// 437.790 us; speedup vs baseline: 1.1532x; 1.0407x over previous
//
#include <hip/hip_runtime.h>
#include <math.h>

// Problem constants
#define BB     32
#define NBANDS 9
#define NCHAN  64
#define NTIME  4096
#define CC     288           // 32*9
#define TLEN   7
#define NSEG   8
#define SEGLEN 512           // NTIME/8
#define NCLASS 4

// ws layout (float-indexed). WS_WF region holds Wh+Wl as _Float16:
// 2 * CC*NCHAN halves = CC*NCHAN floats exactly.
#define WS_WF    0                      // 288*64 floats (= Wh[18432]h + Wl[18432]h)
#define WS_BIAS  (WS_WF + CC*NCHAN)     // 288
#define WS_S1    (WS_BIAS + CC)         // 32*288*8
#define WS_S2    (WS_S1 + BB*CC*NSEG)   // 32*288*8
#define WS_FLAT  (WS_S2 + BB*CC*NSEG)   // 32*4032

typedef _Float16 f16;
typedef __attribute__((ext_vector_type(8))) _Float16 f16x8;
typedef __attribute__((ext_vector_type(4))) float floatx4;

// ---------------- K0: fold renorm(conv_w,2)+BN into split-fp16 W -----------
// Wh/Wl layout: [g][h][c_local]  (A-operand-friendly: c contiguous)
__global__ __launch_bounds__(64) void k0_fold(
    const float* __restrict__ cw, const float* __restrict__ cb,
    const float* __restrict__ gam, const float* __restrict__ bet,
    const float* __restrict__ mu, const float* __restrict__ var,
    f16* __restrict__ Wh, f16* __restrict__ Wl, float* __restrict__ biasf) {
  int c = blockIdx.x;              // 0..287 global channel
  int h = threadIdx.x;             // 0..63
  int g = c >> 5, cc = c & 31;
  float w = cw[c * NCHAN + h];
  float sq = w * w;
#pragma unroll
  for (int off = 32; off; off >>= 1) sq += __shfl_down(sq, off, 64);
  sq = __shfl(sq, 0, 64);
  float norm = sqrtf(sq);
  float scale = fminf(1.0f, 2.0f / fmaxf(norm, 1e-7f));
  float bns = gam[c] / sqrtf(var[c] + 1e-5f);
  float wf = w * scale * bns;
  f16 hi = (f16)wf;
  f16 lo = (f16)(wf - (float)hi);
  int o = g * (NCHAN * 32) + h * 32 + cc;
  Wh[o] = hi;
  Wl[o] = lo;
  if (h == 0) biasf[c] = (cb[c] - mu[c]) * bns + bet[c];
}

// ---------------- K1: split-fp16 MFMA conv + swish + moment sums -----------
// One block per (b,g,seg): D[32c x 512t] = W[32x64] . X[64x512], K=64.
// Precision: w=wh+wl, x=xh+xl (fp16 pairs); D ~= Wh.Xh + Wh.Xl + Wl.Xh
// (error ~2^-23 rel — fp32-grade; bf16 single failed at absmax 7).
// Layouts (HW-verified m89/m91/m120): A[m=lane&15][k=quad*8+j],
// B[k=quad*8+j][n=lane&15], C/D row=quad*4+reg, col=lane&15.
// Each thread loads float4; the 4 values feed 4 different 16-col tiles
// (col<->t mapping is per-tile bijective; sums over t make it free).
__global__ __launch_bounds__(256, 2) void k1_conv(
    const float* __restrict__ x, const f16* __restrict__ Wh,
    const f16* __restrict__ Wl, const float* __restrict__ biasf,
    float* __restrict__ S1, float* __restrict__ S2) {
  int gid = blockIdx.x;
  int seg = gid & 7;
  int g = (gid >> 3) % NBANDS;
  int b = gid / (NBANDS * NSEG);
  int tid = threadIdx.x;
  int wave = tid >> 6, lane = tid & 63;
  int quad = lane >> 4, li = lane & 15;

  const float* xp = x + (size_t)(b * NBANDS + g) * NCHAN * NTIME;
  const f16* wh = Wh + g * (NCHAN * 32);
  const f16* wl = Wl + g * (NCHAN * 32);

  // A fragments: afr[mt][kb] elem j -> W[c=mt*16+li][h=kb*32+quad*8+j]
  f16x8 ah[2][2], al[2][2];
#pragma unroll
  for (int mt = 0; mt < 2; ++mt)
#pragma unroll
    for (int kb = 0; kb < 2; ++kb)
#pragma unroll
      for (int j = 0; j < 8; ++j) {
        int idx = (kb * 32 + quad * 8 + j) * 32 + mt * 16 + li;
        ah[mt][kb][j] = wh[idx];
        al[mt][kb][j] = wl[idx];
      }

  // bias for this lane's output rows: c = mt*16 + quad*4 + r
  float biasr[2][4];
#pragma unroll
  for (int mt = 0; mt < 2; ++mt)
#pragma unroll
    for (int r = 0; r < 4; ++r)
      biasr[mt][r] = biasf[g * 32 + mt * 16 + quad * 4 + r];

  float s1a[2][4], s2a[2][4];
#pragma unroll
  for (int mt = 0; mt < 2; ++mt)
#pragma unroll
    for (int r = 0; r < 4; ++r) { s1a[mt][r] = 0.0f; s2a[mt][r] = 0.0f; }

#pragma unroll 1
  for (int ch = 0; ch < 2; ++ch) {
    int tc = seg * SEGLEN + wave * 128 + ch * 64;   // 64-t chunk base
    float4 v4[2][8];                                 // lane li: t = tc+4*li+tau
#pragma unroll
    for (int kb = 0; kb < 2; ++kb)
#pragma unroll
      for (int j = 0; j < 8; ++j)
        v4[kb][j] = *(const float4*)(xp + (size_t)(kb * 32 + quad * 8 + j) * NTIME
                                     + tc + li * 4);
#pragma unroll
    for (int tau = 0; tau < 4; ++tau) {
      f16x8 bh[2], bl[2];
#pragma unroll
      for (int kb = 0; kb < 2; ++kb)
#pragma unroll
        for (int j = 0; j < 8; ++j) {
          float v = ((const float*)&v4[kb][j])[tau];
          f16 hi = (f16)v;
          bh[kb][j] = hi;
          bl[kb][j] = (f16)(v - (float)hi);
        }
      floatx4 acc0 = {0.0f, 0.0f, 0.0f, 0.0f};
      floatx4 acc1 = {0.0f, 0.0f, 0.0f, 0.0f};
#pragma unroll
      for (int kb = 0; kb < 2; ++kb) {
        acc0 = __builtin_amdgcn_mfma_f32_16x16x32_f16(ah[0][kb], bh[kb], acc0, 0, 0, 0);
        acc0 = __builtin_amdgcn_mfma_f32_16x16x32_f16(ah[0][kb], bl[kb], acc0, 0, 0, 0);
        acc0 = __builtin_amdgcn_mfma_f32_16x16x32_f16(al[0][kb], bh[kb], acc0, 0, 0, 0);
        acc1 = __builtin_amdgcn_mfma_f32_16x16x32_f16(ah[1][kb], bh[kb], acc1, 0, 0, 0);
        acc1 = __builtin_amdgcn_mfma_f32_16x16x32_f16(ah[1][kb], bl[kb], acc1, 0, 0, 0);
        acc1 = __builtin_amdgcn_mfma_f32_16x16x32_f16(al[1][kb], bh[kb], acc1, 0, 0, 0);
      }
#pragma unroll
      for (int r = 0; r < 4; ++r) {
        float d0 = acc0[r] + biasr[0][r];
        float d1 = acc1[r] + biasr[1][r];
        float y0 = d0 * __builtin_amdgcn_rcpf(1.0f + __expf(-d0));
        float y1 = d1 * __builtin_amdgcn_rcpf(1.0f + __expf(-d1));
        s1a[0][r] += y0; s2a[0][r] = fmaf(y0, y0, s2a[0][r]);
        s1a[1][r] += y1; s2a[1][r] = fmaf(y1, y1, s2a[1][r]);
      }
    }
  }

  // reduce over the 16 lanes of each quad (cols = times)
#pragma unroll
  for (int off = 8; off; off >>= 1) {
#pragma unroll
    for (int mt = 0; mt < 2; ++mt)
#pragma unroll
      for (int r = 0; r < 4; ++r) {
        s1a[mt][r] += __shfl_down(s1a[mt][r], off, 16);
        s2a[mt][r] += __shfl_down(s2a[mt][r], off, 16);
      }
  }

  __shared__ float part[2][32][4];   // [metric][c][wave]
  if (li == 0) {
#pragma unroll
    for (int mt = 0; mt < 2; ++mt)
#pragma unroll
      for (int r = 0; r < 4; ++r) {
        int c = mt * 16 + quad * 4 + r;
        part[0][c][wave] = s1a[mt][r];
        part[1][c][wave] = s2a[mt][r];
      }
  }
  __syncthreads();
  if (tid < 64) {
    int c = tid >> 1, which = tid & 1;
    float v = part[which][c][0] + part[which][c][1] +
              part[which][c][2] + part[which][c][3];
    size_t o = (size_t)((b * CC) + g * 32 + c) * NSEG + seg;
    if (which == 0) S1[o] = v; else S2[o] = v;
  }
}

// ---------------- K2: tempo features + per-(b,c) 7x2 MHSA + out_proj --------
__global__ __launch_bounds__(256) void k2_attn(
    const float* __restrict__ S1, const float* __restrict__ S2,
    const float* __restrict__ ipw, const float* __restrict__ ipb,
    const float* __restrict__ opw, const float* __restrict__ opb,
    float* __restrict__ flat) {
  const float PSIN[TLEN] = {0.0f, 0.8414709848f, 0.9092974268f, 0.1411200081f,
                            -0.7568024953f, -0.9589242747f, -0.2794154982f};
  const float PCOS[TLEN] = {1.0f, 0.5403023059f, -0.4161468365f, -0.9899924966f,
                            -0.6536436209f, 0.2836621855f, 0.9601702867f};
  int idx = blockIdx.x * blockDim.x + threadIdx.x;
  if (idx >= BB * CC) return;
  int b = idx / CC, c = idx % CC;
  const float* s1 = S1 + (size_t)(b * CC + c) * NSEG;
  const float* s2 = S2 + (size_t)(b * CC + c) * NSEG;

  float yq[TLEN][2];
#pragma unroll
  for (int t = 0; t < TLEN; ++t) {
    float S1w = s1[t] + s1[t + 1];
    float S2w = s2[t] + s2[t + 1];
    float mean = S1w * (1.0f / 1024.0f);
    float var = (S2w - S1w * S1w * (1.0f / 1024.0f)) * (1.0f / 1023.0f);
    var = fminf(fmaxf(var, 1e-6f), 1e6f);
    float rms = sqrtf(S2w * (1.0f / 1024.0f));
    yq[t][0] = __logf(var) + PSIN[t];
    yq[t][1] = rms / mean + PCOS[t];
  }

  const float* W = ipw + c * 12;
  const float* Bp = ipb + c * 6;
  float q[TLEN][2], k[TLEN][2], v[TLEN][2];
#pragma unroll
  for (int t = 0; t < TLEN; ++t) {
#pragma unroll
    for (int f = 0; f < 6; ++f) {
      float val = W[f * 2 + 0] * yq[t][0] + W[f * 2 + 1] * yq[t][1] + Bp[f];
      if (f < 2) q[t][f] = val;
      else if (f < 4) k[t][f - 2] = val;
      else v[t][f - 4] = val;
    }
  }

  float o[TLEN][2];
#pragma unroll
  for (int h = 0; h < 2; ++h) {
#pragma unroll
    for (int t = 0; t < TLEN; ++t) {
      float sc[TLEN];
      float m = -1e30f;
#pragma unroll
      for (int s = 0; s < TLEN; ++s) {
        sc[s] = q[t][h] * k[s][h];
        m = fmaxf(m, sc[s]);
      }
      float sum = 0.0f, acc = 0.0f;
#pragma unroll
      for (int s = 0; s < TLEN; ++s) {
        float e = __expf(sc[s] - m);
        sum += e;
        acc += e * v[s][h];
      }
      o[t][h] = acc / sum;
    }
  }

  const float* Wo = opw + c * 4;
  const float* Bo = opb + c * 2;
  float* out = flat + (size_t)b * (CC * TLEN * 2) + c * (TLEN * 2);
#pragma unroll
  for (int t = 0; t < TLEN; ++t) {
    out[t * 2 + 0] = Wo[0] * o[t][0] + Wo[1] * o[t][1] + Bo[0];
    out[t * 2 + 1] = Wo[2] * o[t][0] + Wo[3] * o[t][1] + Bo[1];
  }
}

// ---------------- K3: classifier with renorm(last_w,0.5) + log_softmax ------
__global__ __launch_bounds__(256) void k3_cls(
    const float* __restrict__ flat, const float* __restrict__ lw,
    const float* __restrict__ lb, float* __restrict__ out) {
  const int FEAT = CC * TLEN * 2;  // 4032
  int b = blockIdx.x;
  int tid = threadIdx.x;
  const float* f = flat + (size_t)b * FEAT;
  float d[NCLASS] = {0, 0, 0, 0}, n2[NCLASS] = {0, 0, 0, 0};
  for (int j = tid; j < FEAT; j += 256) {
    float fv = f[j];
#pragma unroll
    for (int n = 0; n < NCLASS; ++n) {
      float w = lw[n * FEAT + j];
      d[n] = fmaf(fv, w, d[n]);
      n2[n] = fmaf(w, w, n2[n]);
    }
  }
  __shared__ float red[4][8];
  int lane = tid & 63, wave = tid >> 6;
#pragma unroll
  for (int n = 0; n < NCLASS; ++n) {
#pragma unroll
    for (int off = 32; off; off >>= 1) {
      d[n] += __shfl_down(d[n], off, 64);
      n2[n] += __shfl_down(n2[n], off, 64);
    }
  }
  if (lane == 0) {
#pragma unroll
    for (int n = 0; n < NCLASS; ++n) {
      red[wave][n] = d[n];
      red[wave][n + 4] = n2[n];
    }
  }
  __syncthreads();
  if (tid == 0) {
    float logit[NCLASS];
#pragma unroll
    for (int n = 0; n < NCLASS; ++n) {
      float dn = red[0][n] + red[1][n] + red[2][n] + red[3][n];
      float nn = red[0][n + 4] + red[1][n + 4] + red[2][n + 4] + red[3][n + 4];
      float norm = sqrtf(nn);
      float scale = fminf(1.0f, 0.5f / fmaxf(norm, 1e-7f));
      logit[n] = dn * scale + lb[n];
    }
    float m = fmaxf(fmaxf(logit[0], logit[1]), fmaxf(logit[2], logit[3]));
    float s = 0.0f;
#pragma unroll
    for (int n = 0; n < NCLASS; ++n) s += expf(logit[n] - m);
    float ls = logf(s);
#pragma unroll
    for (int n = 0; n < NCLASS; ++n) out[b * NCLASS + n] = logit[n] - m - ls;
  }
}

extern "C" void kernel_launch(void* const* d_in, const int* in_sizes, int n_in,
                              void* d_out, int out_size, void* d_ws, size_t ws_size,
                              hipStream_t stream) {
  const float* x     = (const float*)d_in[0];
  const float* cw    = (const float*)d_in[1];
  const float* cb    = (const float*)d_in[2];
  const float* gam   = (const float*)d_in[3];
  const float* bet   = (const float*)d_in[4];
  const float* mu    = (const float*)d_in[5];
  const float* var   = (const float*)d_in[6];
  const float* ipw   = (const float*)d_in[7];
  const float* ipb   = (const float*)d_in[8];
  const float* opw   = (const float*)d_in[9];
  const float* opb   = (const float*)d_in[10];
  const float* lw    = (const float*)d_in[11];
  const float* lb    = (const float*)d_in[12];
  float* out = (float*)d_out;

  float* ws = (float*)d_ws;
  f16* Wh = (f16*)(ws + WS_WF);
  f16* Wl = Wh + CC * NCHAN;
  float* biasf = ws + WS_BIAS;
  float* S1    = ws + WS_S1;
  float* S2    = ws + WS_S2;
  float* flat  = ws + WS_FLAT;

  k0_fold<<<CC, 64, 0, stream>>>(cw, cb, gam, bet, mu, var, Wh, Wl, biasf);
  k1_conv<<<BB * NBANDS * NSEG, 256, 0, stream>>>(x, Wh, Wl, biasf, S1, S2);
  k2_attn<<<(BB * CC + 255) / 256, 256, 0, stream>>>(S1, S2, ipw, ipb, opw, opb, flat);
  k3_cls<<<BB, 256, 0, stream>>>(flat, lw, lb, out);
}